// Round 1
// 1073.521 us; speedup vs baseline: 1.0915x; 1.0915x over previous
//
#include <hip/hip_runtime.h>
#include <hip/hip_bf16.h>
#include <cstdint>

// ---- problem constants ----
#define B_   2
#define S_   2048
#define H_   1024
#define NH_  16
#define HD_  64
#define YSIZE (B_*S_*H_)          // 4194304
#define ATTN_PER_BH ((size_t)S_*S_)

typedef __bf16 bf16x8 __attribute__((ext_vector_type(8)));
typedef __bf16 bf16x4_t __attribute__((ext_vector_type(4)));
typedef float f32x4 __attribute__((ext_vector_type(4)));

#define MFMA(a, b, c) __builtin_amdgcn_mfma_f32_16x16x32_bf16((a), (b), (c), 0, 0, 0)

__device__ __forceinline__ void gl2lds16(const void* g, void* lds) {
    __builtin_amdgcn_global_load_lds(
        (__attribute__((address_space(1))) void*)g,
        (__attribute__((address_space(3))) void*)lds,
        16, 0, 0);
}

// ---------------- fp32 -> bf16 conversion (enc + 4 weights) ----------------
__global__ __launch_bounds__(256) void k_convert(
    const float* __restrict__ enc, const float* __restrict__ wq,
    const float* __restrict__ wk, const float* __restrict__ wv,
    const float* __restrict__ wo,
    __bf16* __restrict__ encb, __bf16* __restrict__ wqb,
    __bf16* __restrict__ wkb, __bf16* __restrict__ wvb,
    __bf16* __restrict__ wob)
{
    size_t i = ((size_t)blockIdx.x * 256 + threadIdx.x) * 4;
    const float* src; __bf16* dst; size_t off;
    if (i < (size_t)YSIZE) { src = enc; dst = encb; off = i; }
    else {
        size_t j = i - YSIZE; int w = (int)(j >> 20); off = j & 1048575u;
        if      (w == 0) { src = wq; dst = wqb; }
        else if (w == 1) { src = wk; dst = wkb; }
        else if (w == 2) { src = wv; dst = wvb; }
        else             { src = wo; dst = wob; }
    }
    float4 v = *(const float4*)(src + off);
    bf16x4_t o;
    o[0] = (__bf16)v.x; o[1] = (__bf16)v.y; o[2] = (__bf16)v.z; o[3] = (__bf16)v.w;
    *(bf16x4_t*)(dst + off) = o;
}

// ---------------- mask -> bitmask (1 bit per element, [b*S][32] uint64) ----
__global__ __launch_bounds__(256) void k_maskbits(
    const float* __restrict__ mask, unsigned long long* __restrict__ mbits)
{
    __shared__ unsigned char byt[256];
    const int row = blockIdx.x, t = threadIdx.x;
    const float* mrow = mask + (size_t)row * S_;
    float4 a = *(const float4*)(mrow + t * 8);
    float4 b = *(const float4*)(mrow + t * 8 + 4);
    unsigned v = (a.x != 0.f ? 1u : 0u)  | (a.y != 0.f ? 2u : 0u)
               | (a.z != 0.f ? 4u : 0u)  | (a.w != 0.f ? 8u : 0u)
               | (b.x != 0.f ? 16u : 0u) | (b.y != 0.f ? 32u : 0u)
               | (b.z != 0.f ? 64u : 0u) | (b.w != 0.f ? 128u : 0u);
    byt[t] = (unsigned char)v;
    __syncthreads();
    if (t < 32) {
        unsigned long long w = 0;
#pragma unroll
        for (int j = 0; j < 8; ++j)
            w |= (unsigned long long)byt[t * 8 + j] << (8 * j);
        mbits[(size_t)row * 32 + t] = w;
    }
}

// ---------------- generic bf16 NT GEMM: C[m][n] = sum_k A[m][k]*B[n][k] ----
template<int OUTF32>
__global__ __launch_bounds__(256) void k_gemm_nt(
    const __bf16* __restrict__ A, const __bf16* __restrict__ Bm,
    void* __restrict__ Cout, const float* __restrict__ resid,
    int K, int Nrs,
    unsigned Md, unsigned s1, unsigned s2, unsigned Nd, unsigned s3, unsigned s4)
{
    __shared__ __bf16 As[128 * 32];
    __shared__ __bf16 Bs[128 * 32];
    const int tid = threadIdx.x, l = tid & 63, w = tid >> 6;
    const int quad = l >> 4, l16 = l & 15;
    const int row0 = blockIdx.y * 128, col0 = blockIdx.x * 128;
    const int mbase = (w >> 1) * 64, nbase = (w & 1) * 64;

    f32x4 acc[4][4] = {};

    for (int k0 = 0; k0 < K; k0 += 32) {
#pragma unroll
        for (int i = 0; i < 2; ++i) {
            int lc = (w * 2 + i) * 64 + l;
            int r = lc >> 2, p = lc & 3;
            int c = p ^ ((r >> 1) & 3);
            gl2lds16(A + ((size_t)(row0 + r) * K + k0 + c * 8), As + (w * 2 + i) * 512);
            gl2lds16(Bm + ((size_t)(col0 + r) * K + k0 + c * 8), Bs + (w * 2 + i) * 512);
        }
        __syncthreads();
        bf16x8 af[4], bf[4];
#pragma unroll
        for (int mi = 0; mi < 4; ++mi) {
            int r = mbase + mi * 16 + l16;
            int c = quad ^ ((r >> 1) & 3);
            af[mi] = *(const bf16x8*)(As + r * 32 + c * 8);
        }
#pragma unroll
        for (int ni = 0; ni < 4; ++ni) {
            int r = nbase + ni * 16 + l16;
            int c = quad ^ ((r >> 1) & 3);
            bf[ni] = *(const bf16x8*)(Bs + r * 32 + c * 8);
        }
#pragma unroll
        for (int mi = 0; mi < 4; ++mi)
#pragma unroll
            for (int ni = 0; ni < 4; ++ni)
                acc[mi][ni] = MFMA(af[mi], bf[ni], acc[mi][ni]);
        __syncthreads();
    }

#pragma unroll
    for (int mi = 0; mi < 4; ++mi)
#pragma unroll
        for (int ni = 0; ni < 4; ++ni)
#pragma unroll
            for (int rr = 0; rr < 4; ++rr) {
                unsigned gm = row0 + mbase + mi * 16 + quad * 4 + rr;
                unsigned gn = col0 + nbase + ni * 16 + l16;
                size_t addr = (size_t)(gm / Md) * s1 + (size_t)(gm % Md) * s2
                            + (size_t)(gn / Nd) * s3 + (size_t)(gn % Nd) * s4;
                float v = acc[mi][ni][rr];
                if (OUTF32) {
                    ((float*)Cout)[addr] = v + resid[(size_t)gm * Nrs + gn];
                } else {
                    ((__bf16*)Cout)[addr] = (__bf16)v;
                }
            }
}

// ---------------- fused attention ----------------
// grid (S/128, NH, B), 256 threads. Two-pass (max-free) softmax with:
//  - T14 async reg-staging: issue next K/V tile global->reg at iteration top,
//    ds_write after barrier (latency hidden under compute; LDS stays 64 KB)
//  - mask bitmask (1 MB, L2-resident) replaces 1 GB of scalar fp32 mask loads,
//    with wave-uniform all-ones fast path
//  - Ps is wave-private -> no barriers around the P transpose / PV steps
__global__ __launch_bounds__(256, 2) void k_attn(
    const __bf16* __restrict__ Qb, const __bf16* __restrict__ Kb,
    const __bf16* __restrict__ Vtb, const unsigned long long* __restrict__ mbits,
    float* __restrict__ attn, __bf16* __restrict__ AO)
{
    __shared__ __bf16 Qs[128 * 64];   // 16 KB, row=q (64 bf16)
    __shared__ __bf16 Ks[128 * 64];   // 16 KB, row=k-seq (64 bf16)
    __shared__ __bf16 Vts[64 * 128];  // 16 KB, row=d (128 bf16)
    __shared__ __bf16 Ps[128 * 64];   // 16 KB, half of P tile (wave-private rows)

    const int tid = threadIdx.x, l = tid & 63, w = tid >> 6;
    const int quad = l >> 4, l16 = l & 15;
    const int q0 = blockIdx.x * 128, h = blockIdx.y, b = blockIdx.z;
    const size_t headQK = (size_t)(b * NH_ + h) * S_ * HD_;
    const __bf16* Qh = Qb + headQK;
    const __bf16* Kh = Kb + headQK;
    const __bf16* Vth = Vtb + (size_t)h * HD_ * (B_ * S_) + (size_t)b * S_;
    const unsigned long long* mrow = mbits + (size_t)b * S_ * 32;
    float* attnb = attn + (size_t)(b * NH_ + h) * ATTN_PER_BH;

    // stage Q tile once (swizzled source, linear LDS dest)
#pragma unroll
    for (int i = 0; i < 4; ++i) {
        int lc = (w * 4 + i) * 64 + l;
        int r = lc >> 3, p = lc & 7, c = p ^ (r & 7);
        gl2lds16(Qh + ((size_t)(q0 + r) * HD_ + c * 8), Qs + (w * 4 + i) * 512);
    }

    // ---- K/V register staging (T14): global->reg early, reg->LDS late ----
    bf16x8 kreg[4], vreg[4];
    auto loadK = [&](int kt) {
#pragma unroll
        for (int j = 0; j < 4; ++j) {
            int lc = j * 256 + tid;
            kreg[j] = *(const bf16x8*)(Kh + (size_t)kt * (128 * HD_) + lc * 8);
        }
    };
    auto writeK = [&]() {
#pragma unroll
        for (int j = 0; j < 4; ++j) {
            int lc = j * 256 + tid;
            int r = lc >> 3, p = lc & 7, c = p ^ (r & 7);
            *(bf16x8*)(Ks + r * 64 + c * 8) = kreg[j];
        }
    };
    auto loadV = [&](int kt) {
#pragma unroll
        for (int j = 0; j < 4; ++j) {
            int lc = j * 256 + tid;
            int r = lc >> 4, p = lc & 15;
            vreg[j] = *(const bf16x8*)(Vth + (size_t)r * (B_ * S_) + kt * 128 + p * 8);
        }
    };
    auto writeV = [&]() {
#pragma unroll
        for (int j = 0; j < 4; ++j) {
            int lc = j * 256 + tid;
            int r = lc >> 4, p = lc & 15, c = p ^ (r & 15);
            *(bf16x8*)(Vts + r * 128 + c * 8) = vreg[j];
        }
    };

    float rs[2][4] = {{0.f, 0.f, 0.f, 0.f}, {0.f, 0.f, 0.f, 0.f}};

    // ---------- pass 1: rowsums of exp ----------
    loadK(0);
    writeK();                // compiler waits vmcnt before ds_write
    __syncthreads();         // also drains Q gl2lds

    for (int kt = 0; kt < 16; ++kt) {
        if (kt < 15) loadK(kt + 1);   // issue early; hidden under compute

        f32x4 sa[2][8] = {};
#pragma unroll
        for (int ks = 0; ks < 2; ++ks) {
            bf16x8 af[2];
#pragma unroll
            for (int mi = 0; mi < 2; ++mi) {
                int r = w * 32 + mi * 16 + l16;
                int c = (ks * 4 + quad) ^ (r & 7);
                af[mi] = *(const bf16x8*)(Qs + r * 64 + c * 8);
            }
#pragma unroll
            for (int nt = 0; nt < 8; ++nt) {
                int r = nt * 16 + l16;
                int c = (ks * 4 + quad) ^ (r & 7);
                bf16x8 bv = *(const bf16x8*)(Ks + r * 64 + c * 8);
#pragma unroll
                for (int mi = 0; mi < 2; ++mi)
                    sa[mi][nt] = MFMA(af[mi], bv, sa[mi][nt]);
            }
        }

        // mask bits + exp + rowsum
        unsigned long long mwx[2][4], mwy[2][4];
        unsigned long long andv = ~0ull;
#pragma unroll
        for (int mi = 0; mi < 2; ++mi)
#pragma unroll
            for (int rr = 0; rr < 4; ++rr) {
                int rowq = q0 + w * 32 + mi * 16 + quad * 4 + rr;
                ulonglong2 mv = *(const ulonglong2*)(mrow + (size_t)rowq * 32 + kt * 2);
                mwx[mi][rr] = mv.x; mwy[mi][rr] = mv.y;
                andv &= mv.x & mv.y;
            }
        if (__all(andv == ~0ull)) {
#pragma unroll
            for (int mi = 0; mi < 2; ++mi)
#pragma unroll
                for (int nt = 0; nt < 8; ++nt)
#pragma unroll
                    for (int rr = 0; rr < 4; ++rr)
                        rs[mi][rr] += __expf(sa[mi][nt][rr] * 0.125f);
        } else {
#pragma unroll
            for (int mi = 0; mi < 2; ++mi)
#pragma unroll
                for (int rr = 0; rr < 4; ++rr) {
                    unsigned long long tx = mwx[mi][rr] >> l16;
                    unsigned long long ty = mwy[mi][rr] >> l16;
#pragma unroll
                    for (int nt = 0; nt < 8; ++nt) {
                        unsigned long long t = (nt & 4) ? ty : tx;
                        unsigned ok = (unsigned)(t >> ((nt & 3) * 16)) & 1u;
                        rs[mi][rr] += ok ? __expf(sa[mi][nt][rr] * 0.125f) : 0.f;
                    }
                }
        }
        __syncthreads();               // all waves done reading Ks
        if (kt < 15) writeK();
        __syncthreads();               // Ks[kt+1] visible
    }

    float inv_l[2][4];
#pragma unroll
    for (int mi = 0; mi < 2; ++mi)
#pragma unroll
        for (int rr = 0; rr < 4; ++rr) {
            float v = rs[mi][rr];
            v += __shfl_xor(v, 1); v += __shfl_xor(v, 2);
            v += __shfl_xor(v, 4); v += __shfl_xor(v, 8);
            inv_l[mi][rr] = 1.0f / v;
        }

    f32x4 oa[2][4] = {};

    // ---------- pass 2: normalize, write P, accumulate O ----------
    loadK(0); loadV(0);
    writeK(); writeV();
    __syncthreads();

    for (int kt = 0; kt < 16; ++kt) {
        if (kt < 15) { loadK(kt + 1); loadV(kt + 1); }

        f32x4 sa[2][8] = {};
#pragma unroll
        for (int ks = 0; ks < 2; ++ks) {
            bf16x8 af[2];
#pragma unroll
            for (int mi = 0; mi < 2; ++mi) {
                int r = w * 32 + mi * 16 + l16;
                int c = (ks * 4 + quad) ^ (r & 7);
                af[mi] = *(const bf16x8*)(Qs + r * 64 + c * 8);
            }
#pragma unroll
            for (int nt = 0; nt < 8; ++nt) {
                int r = nt * 16 + l16;
                int c = (ks * 4 + quad) ^ (r & 7);
                bf16x8 bv = *(const bf16x8*)(Ks + r * 64 + c * 8);
#pragma unroll
                for (int mi = 0; mi < 2; ++mi)
                    sa[mi][nt] = MFMA(af[mi], bv, sa[mi][nt]);
            }
        }

        // normalize + write P (fp32) to output
        unsigned long long mwx[2][4], mwy[2][4];
        unsigned long long andv = ~0ull;
#pragma unroll
        for (int mi = 0; mi < 2; ++mi)
#pragma unroll
            for (int rr = 0; rr < 4; ++rr) {
                int rowq = q0 + w * 32 + mi * 16 + quad * 4 + rr;
                ulonglong2 mv = *(const ulonglong2*)(mrow + (size_t)rowq * 32 + kt * 2);
                mwx[mi][rr] = mv.x; mwy[mi][rr] = mv.y;
                andv &= mv.x & mv.y;
            }
        if (__all(andv == ~0ull)) {
#pragma unroll
            for (int mi = 0; mi < 2; ++mi)
#pragma unroll
                for (int rr = 0; rr < 4; ++rr) {
                    int rowg = q0 + w * 32 + mi * 16 + quad * 4 + rr;
                    float il = inv_l[mi][rr];
#pragma unroll
                    for (int nt = 0; nt < 8; ++nt) {
                        float p = __expf(sa[mi][nt][rr] * 0.125f) * il;
                        sa[mi][nt][rr] = p;
                        attnb[(size_t)rowg * S_ + kt * 128 + nt * 16 + l16] = p;
                    }
                }
        } else {
#pragma unroll
            for (int mi = 0; mi < 2; ++mi)
#pragma unroll
                for (int rr = 0; rr < 4; ++rr) {
                    int rowg = q0 + w * 32 + mi * 16 + quad * 4 + rr;
                    float il = inv_l[mi][rr];
                    unsigned long long tx = mwx[mi][rr] >> l16;
                    unsigned long long ty = mwy[mi][rr] >> l16;
#pragma unroll
                    for (int nt = 0; nt < 8; ++nt) {
                        unsigned long long t = (nt & 4) ? ty : tx;
                        unsigned ok = (unsigned)(t >> ((nt & 3) * 16)) & 1u;
                        float p = ok ? __expf(sa[mi][nt][rr] * 0.125f) * il : 0.f;
                        sa[mi][nt][rr] = p;
                        attnb[(size_t)rowg * S_ + kt * 128 + nt * 16 + l16] = p;
                    }
                }
        }

        // half 0: P cols 0..63 -> Ps (wave-private rows, no barrier), then PV
#pragma unroll
        for (int mi = 0; mi < 2; ++mi) {
            int m0 = w * 32 + mi * 16 + quad * 4;
#pragma unroll
            for (int nt = 0; nt < 4; ++nt) {
                int kl = nt * 16 + l16;
#pragma unroll
                for (int rr = 0; rr < 4; ++rr) {
                    int m = m0 + rr;
                    int ch = (kl >> 3) ^ (m & 7);
                    Ps[m * 64 + ch * 8 + (kl & 7)] = (__bf16)sa[mi][nt][rr];
                }
            }
        }
#pragma unroll
        for (int ks = 0; ks < 2; ++ks) {
            bf16x8 af[2];
#pragma unroll
            for (int mi = 0; mi < 2; ++mi) {
                int r = w * 32 + mi * 16 + l16;
                int c = (ks * 4 + quad) ^ (r & 7);
                af[mi] = *(const bf16x8*)(Ps + r * 64 + c * 8);
            }
#pragma unroll
            for (int nt = 0; nt < 4; ++nt) {
                int dr = nt * 16 + l16;
                int vc = (ks * 4 + quad) ^ (dr & 15);
                bf16x8 bv = *(const bf16x8*)(Vts + dr * 128 + vc * 8);
#pragma unroll
                for (int mi = 0; mi < 2; ++mi)
                    oa[mi][nt] = MFMA(af[mi], bv, oa[mi][nt]);
            }
        }
        // half 1: P cols 64..127
#pragma unroll
        for (int mi = 0; mi < 2; ++mi) {
            int m0 = w * 32 + mi * 16 + quad * 4;
#pragma unroll
            for (int nt = 4; nt < 8; ++nt) {
                int kl = (nt - 4) * 16 + l16;
#pragma unroll
                for (int rr = 0; rr < 4; ++rr) {
                    int m = m0 + rr;
                    int ch = (kl >> 3) ^ (m & 7);
                    Ps[m * 64 + ch * 8 + (kl & 7)] = (__bf16)sa[mi][nt][rr];
                }
            }
        }
#pragma unroll
        for (int ks = 0; ks < 2; ++ks) {
            bf16x8 af[2];
#pragma unroll
            for (int mi = 0; mi < 2; ++mi) {
                int r = w * 32 + mi * 16 + l16;
                int c = (ks * 4 + quad) ^ (r & 7);
                af[mi] = *(const bf16x8*)(Ps + r * 64 + c * 8);
            }
#pragma unroll
            for (int nt = 0; nt < 4; ++nt) {
                int dr = nt * 16 + l16;
                int vc = (8 + ks * 4 + quad) ^ (dr & 15);
                bf16x8 bv = *(const bf16x8*)(Vts + dr * 128 + vc * 8);
#pragma unroll
                for (int mi = 0; mi < 2; ++mi)
                    oa[mi][nt] = MFMA(af[mi], bv, oa[mi][nt]);
            }
        }
        __syncthreads();               // all waves done reading Ks/Vts
        if (kt < 15) { writeK(); writeV(); }
        __syncthreads();               // new tiles visible
    }

    // write attention output in (b, s, h, d) bf16 layout for the O-projection
#pragma unroll
    for (int mi = 0; mi < 2; ++mi)
#pragma unroll
        for (int nt = 0; nt < 4; ++nt)
#pragma unroll
            for (int rr = 0; rr < 4; ++rr) {
                int sg = b * S_ + q0 + w * 32 + mi * 16 + quad * 4 + rr;
                int f = h * HD_ + nt * 16 + l16;
                AO[(size_t)sg * H_ + f] = (__bf16)oa[mi][nt][rr];
            }
}

// ---------------- LayerNorm (in-place on d_out y region) ----------------
__global__ __launch_bounds__(256) void k_ln(
    float* __restrict__ x, const float* __restrict__ lw, const float* __restrict__ lb)
{
    __shared__ float red[8];
    const int row = blockIdx.x, tid = threadIdx.x;
    float4 v = *(float4*)(x + (size_t)row * H_ + tid * 4);
    float s = v.x + v.y + v.z + v.w;
    float ss = v.x * v.x + v.y * v.y + v.z * v.z + v.w * v.w;
#pragma unroll
    for (int o = 1; o < 64; o <<= 1) { s += __shfl_xor(s, o); ss += __shfl_xor(ss, o); }
    const int w = tid >> 6;
    if ((tid & 63) == 0) { red[w] = s; red[4 + w] = ss; }
    __syncthreads();
    s = red[0] + red[1] + red[2] + red[3];
    ss = red[4] + red[5] + red[6] + red[7];
    float mu = s * (1.0f / H_);
    float var = ss * (1.0f / H_) - mu * mu;
    float rstd = rsqrtf(var + 1e-6f);
    float4 wv = *(const float4*)(lw + tid * 4);
    float4 bv = *(const float4*)(lb + tid * 4);
    float4 y;
    y.x = (v.x - mu) * rstd * wv.x + bv.x;
    y.y = (v.y - mu) * rstd * wv.y + bv.y;
    y.z = (v.z - mu) * rstd * wv.z + bv.z;
    y.w = (v.w - mu) * rstd * wv.w + bv.w;
    *(float4*)(x + (size_t)row * H_ + tid * 4) = y;
}

// ---------------- launch ----------------
extern "C" void kernel_launch(void* const* d_in, const int* in_sizes, int n_in,
                              void* d_out, int out_size, void* d_ws, size_t ws_size,
                              hipStream_t stream)
{
    const float* enc  = (const float*)d_in[0];
    const float* mask = (const float*)d_in[1];
    const float* WQ   = (const float*)d_in[2];
    const float* WK   = (const float*)d_in[3];
    const float* WV   = (const float*)d_in[4];
    const float* WO   = (const float*)d_in[5];
    const float* lnw  = (const float*)d_in[6];
    const float* lnb  = (const float*)d_in[7];

    float* y    = (float*)d_out;          // [B,S,H] fp32
    float* attn = y + YSIZE;              // [B,NH,S,S] fp32

    char* ws = (char*)d_ws;
    __bf16* encb = (__bf16*)(ws);                    // 8 MB (dead after V GEMM)
    __bf16* wqb  = (__bf16*)(ws + (8ull  << 20));    // 2 MB
    __bf16* wkb  = (__bf16*)(ws + (10ull << 20));
    __bf16* wvb  = (__bf16*)(ws + (12ull << 20));
    __bf16* wob  = (__bf16*)(ws + (14ull << 20));
    __bf16* Qb   = (__bf16*)(ws + (16ull << 20));    // 8 MB  (b,h,s,d)
    __bf16* Kb   = (__bf16*)(ws + (24ull << 20));    // 8 MB  (b,h,s,d)
    __bf16* Vtb  = (__bf16*)(ws + (32ull << 20));    // 8 MB  (h,d,b,s)
    __bf16* AO   = (__bf16*)(ws + (40ull << 20));    // 8 MB  (b,s,h,d)
    // 1 MB mask bitmask overlays encb region (only live during/after k_maskbits,
    // which runs after the last consumer of encb)
    unsigned long long* mbits = (unsigned long long*)ws;

    k_convert<<<8192, 256, 0, stream>>>(enc, WQ, WK, WV, WO, encb, wqb, wkb, wvb, wob);

    dim3 gQK(8, 32);   // N=1024 tiles, M=4096 tiles
    k_gemm_nt<0><<<gQK, 256, 0, stream>>>(encb, wqb, Qb, nullptr, H_, 0,
                                          2048u, 2097152u, 64u, 64u, 131072u, 1u);
    k_gemm_nt<0><<<gQK, 256, 0, stream>>>(encb, wkb, Kb, nullptr, H_, 0,
                                          2048u, 2097152u, 64u, 64u, 131072u, 1u);
    dim3 gV(32, 8);    // N=4096 tiles, M=1024 tiles  (V^T: addr = m*4096 + n)
    k_gemm_nt<0><<<gV, 256, 0, stream>>>(wvb, encb, Vtb, nullptr, H_, 0,
                                         4096u, 0u, 4096u, 4096u, 0u, 1u);

    k_maskbits<<<B_ * S_, 256, 0, stream>>>(mask, mbits);

    dim3 gA(S_ / 128, NH_, B_);
    k_attn<<<gA, 256, 0, stream>>>(Qb, Kb, Vtb, mbits, attn, AO);

    // O-proj + residual, fp32 into d_out y region: addr = gm*1024 + gn
    k_gemm_nt<1><<<gQK, 256, 0, stream>>>(AO, wob, y, enc, H_, H_,
                                          4096u, 0u, 1024u, 1024u, 0u, 1u);

    k_ln<<<YSIZE / H_, 256, 0, stream>>>(y, lnw, lnb);
}

// Round 2
// 1006.677 us; speedup vs baseline: 1.1640x; 1.0664x over previous
//
#include <hip/hip_runtime.h>
#include <hip/hip_bf16.h>
#include <cstdint>

// ---- problem constants ----
#define B_   2
#define S_   2048
#define H_   1024
#define NH_  16
#define HD_  64
#define YSIZE (B_*S_*H_)          // 4194304
#define ATTN_PER_BH ((size_t)S_*S_)

typedef __bf16 bf16x8 __attribute__((ext_vector_type(8)));
typedef __bf16 bf16x4_t __attribute__((ext_vector_type(4)));
typedef float f32x4 __attribute__((ext_vector_type(4)));

#define MFMA(a, b, c) __builtin_amdgcn_mfma_f32_16x16x32_bf16((a), (b), (c), 0, 0, 0)

__device__ __forceinline__ void gl2lds16(const void* g, void* lds) {
    __builtin_amdgcn_global_load_lds(
        (__attribute__((address_space(1))) void*)g,
        (__attribute__((address_space(3))) void*)lds,
        16, 0, 0);
}

// ---------------- fp32 -> bf16 conversion (enc + 4 weights) ----------------
__global__ __launch_bounds__(256) void k_convert(
    const float* __restrict__ enc, const float* __restrict__ wq,
    const float* __restrict__ wk, const float* __restrict__ wv,
    const float* __restrict__ wo,
    __bf16* __restrict__ encb, __bf16* __restrict__ wqb,
    __bf16* __restrict__ wkb, __bf16* __restrict__ wvb,
    __bf16* __restrict__ wob)
{
    size_t i = ((size_t)blockIdx.x * 256 + threadIdx.x) * 4;
    const float* src; __bf16* dst; size_t off;
    if (i < (size_t)YSIZE) { src = enc; dst = encb; off = i; }
    else {
        size_t j = i - YSIZE; int w = (int)(j >> 20); off = j & 1048575u;
        if      (w == 0) { src = wq; dst = wqb; }
        else if (w == 1) { src = wk; dst = wkb; }
        else if (w == 2) { src = wv; dst = wvb; }
        else             { src = wo; dst = wob; }
    }
    float4 v = *(const float4*)(src + off);
    bf16x4_t o;
    o[0] = (__bf16)v.x; o[1] = (__bf16)v.y; o[2] = (__bf16)v.z; o[3] = (__bf16)v.w;
    *(bf16x4_t*)(dst + off) = o;
}

// ---------------- mask -> bitmask (1 bit per element, [b*S][32] uint64) ----
__global__ __launch_bounds__(256) void k_maskbits(
    const float* __restrict__ mask, unsigned long long* __restrict__ mbits)
{
    __shared__ unsigned char byt[256];
    const int row = blockIdx.x, t = threadIdx.x;
    const float* mrow = mask + (size_t)row * S_;
    float4 a = *(const float4*)(mrow + t * 8);
    float4 b = *(const float4*)(mrow + t * 8 + 4);
    unsigned v = (a.x != 0.f ? 1u : 0u)  | (a.y != 0.f ? 2u : 0u)
               | (a.z != 0.f ? 4u : 0u)  | (a.w != 0.f ? 8u : 0u)
               | (b.x != 0.f ? 16u : 0u) | (b.y != 0.f ? 32u : 0u)
               | (b.z != 0.f ? 64u : 0u) | (b.w != 0.f ? 128u : 0u);
    byt[t] = (unsigned char)v;
    __syncthreads();
    if (t < 32) {
        unsigned long long w = 0;
#pragma unroll
        for (int j = 0; j < 8; ++j)
            w |= (unsigned long long)byt[t * 8 + j] << (8 * j);
        mbits[(size_t)row * 32 + t] = w;
    }
}

// ---------------- generic bf16 NT GEMM: C[m][n] = sum_k A[m][k]*B[n][k] ----
template<int OUTF32>
__global__ __launch_bounds__(256) void k_gemm_nt(
    const __bf16* __restrict__ A, const __bf16* __restrict__ Bm,
    void* __restrict__ Cout, const float* __restrict__ resid,
    int K, int Nrs,
    unsigned Md, unsigned s1, unsigned s2, unsigned Nd, unsigned s3, unsigned s4)
{
    __shared__ __bf16 As[128 * 32];
    __shared__ __bf16 Bs[128 * 32];
    const int tid = threadIdx.x, l = tid & 63, w = tid >> 6;
    const int quad = l >> 4, l16 = l & 15;
    const int row0 = blockIdx.y * 128, col0 = blockIdx.x * 128;
    const int mbase = (w >> 1) * 64, nbase = (w & 1) * 64;

    f32x4 acc[4][4] = {};

    for (int k0 = 0; k0 < K; k0 += 32) {
#pragma unroll
        for (int i = 0; i < 2; ++i) {
            int lc = (w * 2 + i) * 64 + l;
            int r = lc >> 2, p = lc & 3;
            int c = p ^ ((r >> 1) & 3);
            gl2lds16(A + ((size_t)(row0 + r) * K + k0 + c * 8), As + (w * 2 + i) * 512);
            gl2lds16(Bm + ((size_t)(col0 + r) * K + k0 + c * 8), Bs + (w * 2 + i) * 512);
        }
        __syncthreads();
        bf16x8 af[4], bf[4];
#pragma unroll
        for (int mi = 0; mi < 4; ++mi) {
            int r = mbase + mi * 16 + l16;
            int c = quad ^ ((r >> 1) & 3);
            af[mi] = *(const bf16x8*)(As + r * 32 + c * 8);
        }
#pragma unroll
        for (int ni = 0; ni < 4; ++ni) {
            int r = nbase + ni * 16 + l16;
            int c = quad ^ ((r >> 1) & 3);
            bf[ni] = *(const bf16x8*)(Bs + r * 32 + c * 8);
        }
#pragma unroll
        for (int mi = 0; mi < 4; ++mi)
#pragma unroll
            for (int ni = 0; ni < 4; ++ni)
                acc[mi][ni] = MFMA(af[mi], bf[ni], acc[mi][ni]);
        __syncthreads();
    }

#pragma unroll
    for (int mi = 0; mi < 4; ++mi)
#pragma unroll
        for (int ni = 0; ni < 4; ++ni)
#pragma unroll
            for (int rr = 0; rr < 4; ++rr) {
                unsigned gm = row0 + mbase + mi * 16 + quad * 4 + rr;
                unsigned gn = col0 + nbase + ni * 16 + l16;
                size_t addr = (size_t)(gm / Md) * s1 + (size_t)(gm % Md) * s2
                            + (size_t)(gn / Nd) * s3 + (size_t)(gn % Nd) * s4;
                float v = acc[mi][ni][rr];
                if (OUTF32) {
                    ((float*)Cout)[addr] = v + resid[(size_t)gm * Nrs + gn];
                } else {
                    ((__bf16*)Cout)[addr] = (__bf16)v;
                }
            }
}

// ---------------- fused attention ----------------
// 1D grid of 512 blocks with XCD-chunked swizzle: each XCD owns 4 (b,h)
// pairs x 16 q-blocks, so K/V (512 KB/pair) stays L2-resident per XCD.
// Non-temporal stores for the 536 MB attn stream keep it from evicting K/V.
__global__ __launch_bounds__(256, 2) void k_attn(
    const __bf16* __restrict__ Qb, const __bf16* __restrict__ Kb,
    const __bf16* __restrict__ Vtb, const unsigned long long* __restrict__ mbits,
    float* __restrict__ attn, __bf16* __restrict__ AO)
{
    __shared__ __bf16 Qs[128 * 64];   // 16 KB, row=q (64 bf16)
    __shared__ __bf16 Ks[128 * 64];   // 16 KB, row=k-seq (64 bf16)
    __shared__ __bf16 Vts[64 * 128];  // 16 KB, row=d (128 bf16)
    __shared__ __bf16 Ps[128 * 64];   // 16 KB, half of P tile (wave-private rows)

    const int tid = threadIdx.x, l = tid & 63, w = tid >> 6;
    const int quad = l >> 4, l16 = l & 15;

    // XCD-chunked swizzle (nwg=512, 8 XCDs, 512%8==0 -> bijective)
    const int wg = blockIdx.x;
    const int logical = (wg & 7) * 64 + (wg >> 3);
    const int qb = logical & 15;            // q-block within pair
    const int pair = logical >> 4;          // 0..31
    const int h = pair & 15, b = pair >> 4;

    const int q0 = qb * 128;
    const size_t headQK = (size_t)(b * NH_ + h) * S_ * HD_;
    const __bf16* Qh = Qb + headQK;
    const __bf16* Kh = Kb + headQK;
    const __bf16* Vth = Vtb + (size_t)h * HD_ * (B_ * S_) + (size_t)b * S_;
    const unsigned long long* mrow = mbits + (size_t)b * S_ * 32;
    float* attnb = attn + (size_t)(b * NH_ + h) * ATTN_PER_BH;

    // stage Q tile once (swizzled source, linear LDS dest)
#pragma unroll
    for (int i = 0; i < 4; ++i) {
        int lc = (w * 4 + i) * 64 + l;
        int r = lc >> 3, p = lc & 7, c = p ^ (r & 7);
        gl2lds16(Qh + ((size_t)(q0 + r) * HD_ + c * 8), Qs + (w * 4 + i) * 512);
    }

    // ---- K/V register staging (T14): global->reg early, reg->LDS late ----
    bf16x8 kreg[4], vreg[4];
    auto loadK = [&](int kt) {
#pragma unroll
        for (int j = 0; j < 4; ++j) {
            int lc = j * 256 + tid;
            kreg[j] = *(const bf16x8*)(Kh + (size_t)kt * (128 * HD_) + lc * 8);
        }
    };
    auto writeK = [&]() {
#pragma unroll
        for (int j = 0; j < 4; ++j) {
            int lc = j * 256 + tid;
            int r = lc >> 3, p = lc & 7, c = p ^ (r & 7);
            *(bf16x8*)(Ks + r * 64 + c * 8) = kreg[j];
        }
    };
    auto loadV = [&](int kt) {
#pragma unroll
        for (int j = 0; j < 4; ++j) {
            int lc = j * 256 + tid;
            int r = lc >> 4, p = lc & 15;
            vreg[j] = *(const bf16x8*)(Vth + (size_t)r * (B_ * S_) + kt * 128 + p * 8);
        }
    };
    auto writeV = [&]() {
#pragma unroll
        for (int j = 0; j < 4; ++j) {
            int lc = j * 256 + tid;
            int r = lc >> 4, p = lc & 15, c = p ^ (r & 15);
            *(bf16x8*)(Vts + r * 128 + c * 8) = vreg[j];
        }
    };

    float rs[2][4] = {{0.f, 0.f, 0.f, 0.f}, {0.f, 0.f, 0.f, 0.f}};

    // ---------- pass 1: rowsums of exp ----------
    loadK(0);
    writeK();                // compiler waits vmcnt before ds_write
    __syncthreads();         // also drains Q gl2lds

    for (int kt = 0; kt < 16; ++kt) {
        if (kt < 15) loadK(kt + 1);   // issue early; hidden under compute

        f32x4 sa[2][8] = {};
#pragma unroll
        for (int ks = 0; ks < 2; ++ks) {
            bf16x8 af[2];
#pragma unroll
            for (int mi = 0; mi < 2; ++mi) {
                int r = w * 32 + mi * 16 + l16;
                int c = (ks * 4 + quad) ^ (r & 7);
                af[mi] = *(const bf16x8*)(Qs + r * 64 + c * 8);
            }
#pragma unroll
            for (int nt = 0; nt < 8; ++nt) {
                int r = nt * 16 + l16;
                int c = (ks * 4 + quad) ^ (r & 7);
                bf16x8 bv = *(const bf16x8*)(Ks + r * 64 + c * 8);
#pragma unroll
                for (int mi = 0; mi < 2; ++mi)
                    sa[mi][nt] = MFMA(af[mi], bv, sa[mi][nt]);
            }
        }

        // mask bits + exp + rowsum
        unsigned long long mwx[2][4], mwy[2][4];
        unsigned long long andv = ~0ull;
#pragma unroll
        for (int mi = 0; mi < 2; ++mi)
#pragma unroll
            for (int rr = 0; rr < 4; ++rr) {
                int rowq = q0 + w * 32 + mi * 16 + quad * 4 + rr;
                ulonglong2 mv = *(const ulonglong2*)(mrow + (size_t)rowq * 32 + kt * 2);
                mwx[mi][rr] = mv.x; mwy[mi][rr] = mv.y;
                andv &= mv.x & mv.y;
            }
        if (__all(andv == ~0ull)) {
#pragma unroll
            for (int mi = 0; mi < 2; ++mi)
#pragma unroll
                for (int nt = 0; nt < 8; ++nt)
#pragma unroll
                    for (int rr = 0; rr < 4; ++rr)
                        rs[mi][rr] += __expf(sa[mi][nt][rr] * 0.125f);
        } else {
#pragma unroll
            for (int mi = 0; mi < 2; ++mi)
#pragma unroll
                for (int rr = 0; rr < 4; ++rr) {
                    unsigned long long tx = mwx[mi][rr] >> l16;
                    unsigned long long ty = mwy[mi][rr] >> l16;
#pragma unroll
                    for (int nt = 0; nt < 8; ++nt) {
                        unsigned long long t = (nt & 4) ? ty : tx;
                        unsigned ok = (unsigned)(t >> ((nt & 3) * 16)) & 1u;
                        rs[mi][rr] += ok ? __expf(sa[mi][nt][rr] * 0.125f) : 0.f;
                    }
                }
        }
        __syncthreads();               // all waves done reading Ks
        if (kt < 15) writeK();
        __syncthreads();               // Ks[kt+1] visible
    }

    float inv_l[2][4];
#pragma unroll
    for (int mi = 0; mi < 2; ++mi)
#pragma unroll
        for (int rr = 0; rr < 4; ++rr) {
            float v = rs[mi][rr];
            v += __shfl_xor(v, 1); v += __shfl_xor(v, 2);
            v += __shfl_xor(v, 4); v += __shfl_xor(v, 8);
            inv_l[mi][rr] = 1.0f / v;
        }

    f32x4 oa[2][4] = {};

    // ---------- pass 2: normalize, write P, accumulate O ----------
    loadK(0); loadV(0);
    writeK(); writeV();
    __syncthreads();

    for (int kt = 0; kt < 16; ++kt) {
        if (kt < 15) { loadK(kt + 1); loadV(kt + 1); }

        f32x4 sa[2][8] = {};
#pragma unroll
        for (int ks = 0; ks < 2; ++ks) {
            bf16x8 af[2];
#pragma unroll
            for (int mi = 0; mi < 2; ++mi) {
                int r = w * 32 + mi * 16 + l16;
                int c = (ks * 4 + quad) ^ (r & 7);
                af[mi] = *(const bf16x8*)(Qs + r * 64 + c * 8);
            }
#pragma unroll
            for (int nt = 0; nt < 8; ++nt) {
                int r = nt * 16 + l16;
                int c = (ks * 4 + quad) ^ (r & 7);
                bf16x8 bv = *(const bf16x8*)(Ks + r * 64 + c * 8);
#pragma unroll
                for (int mi = 0; mi < 2; ++mi)
                    sa[mi][nt] = MFMA(af[mi], bv, sa[mi][nt]);
            }
        }

        // normalize + write P (fp32, non-temporal) to output
        unsigned long long mwx[2][4], mwy[2][4];
        unsigned long long andv = ~0ull;
#pragma unroll
        for (int mi = 0; mi < 2; ++mi)
#pragma unroll
            for (int rr = 0; rr < 4; ++rr) {
                int rowq = q0 + w * 32 + mi * 16 + quad * 4 + rr;
                ulonglong2 mv = *(const ulonglong2*)(mrow + (size_t)rowq * 32 + kt * 2);
                mwx[mi][rr] = mv.x; mwy[mi][rr] = mv.y;
                andv &= mv.x & mv.y;
            }
        if (__all(andv == ~0ull)) {
#pragma unroll
            for (int mi = 0; mi < 2; ++mi)
#pragma unroll
                for (int rr = 0; rr < 4; ++rr) {
                    int rowg = q0 + w * 32 + mi * 16 + quad * 4 + rr;
                    float il = inv_l[mi][rr];
#pragma unroll
                    for (int nt = 0; nt < 8; ++nt) {
                        float p = __expf(sa[mi][nt][rr] * 0.125f) * il;
                        sa[mi][nt][rr] = p;
                        __builtin_nontemporal_store(
                            p, attnb + (size_t)rowg * S_ + kt * 128 + nt * 16 + l16);
                    }
                }
        } else {
#pragma unroll
            for (int mi = 0; mi < 2; ++mi)
#pragma unroll
                for (int rr = 0; rr < 4; ++rr) {
                    int rowg = q0 + w * 32 + mi * 16 + quad * 4 + rr;
                    float il = inv_l[mi][rr];
                    unsigned long long tx = mwx[mi][rr] >> l16;
                    unsigned long long ty = mwy[mi][rr] >> l16;
#pragma unroll
                    for (int nt = 0; nt < 8; ++nt) {
                        unsigned long long t = (nt & 4) ? ty : tx;
                        unsigned ok = (unsigned)(t >> ((nt & 3) * 16)) & 1u;
                        float p = ok ? __expf(sa[mi][nt][rr] * 0.125f) * il : 0.f;
                        sa[mi][nt][rr] = p;
                        __builtin_nontemporal_store(
                            p, attnb + (size_t)rowg * S_ + kt * 128 + nt * 16 + l16);
                    }
                }
        }

        // half 0: P cols 0..63 -> Ps (wave-private rows, no barrier), then PV
#pragma unroll
        for (int mi = 0; mi < 2; ++mi) {
            int m0 = w * 32 + mi * 16 + quad * 4;
#pragma unroll
            for (int nt = 0; nt < 4; ++nt) {
                int kl = nt * 16 + l16;
#pragma unroll
                for (int rr = 0; rr < 4; ++rr) {
                    int m = m0 + rr;
                    int ch = (kl >> 3) ^ (m & 7);
                    Ps[m * 64 + ch * 8 + (kl & 7)] = (__bf16)sa[mi][nt][rr];
                }
            }
        }
#pragma unroll
        for (int ks = 0; ks < 2; ++ks) {
            bf16x8 af[2];
#pragma unroll
            for (int mi = 0; mi < 2; ++mi) {
                int r = w * 32 + mi * 16 + l16;
                int c = (ks * 4 + quad) ^ (r & 7);
                af[mi] = *(const bf16x8*)(Ps + r * 64 + c * 8);
            }
#pragma unroll
            for (int nt = 0; nt < 4; ++nt) {
                int dr = nt * 16 + l16;
                int vc = (ks * 4 + quad) ^ (dr & 15);
                bf16x8 bv = *(const bf16x8*)(Vts + dr * 128 + vc * 8);
#pragma unroll
                for (int mi = 0; mi < 2; ++mi)
                    oa[mi][nt] = MFMA(af[mi], bv, oa[mi][nt]);
            }
        }
        // half 1: P cols 64..127
#pragma unroll
        for (int mi = 0; mi < 2; ++mi) {
            int m0 = w * 32 + mi * 16 + quad * 4;
#pragma unroll
            for (int nt = 4; nt < 8; ++nt) {
                int kl = (nt - 4) * 16 + l16;
#pragma unroll
                for (int rr = 0; rr < 4; ++rr) {
                    int m = m0 + rr;
                    int ch = (kl >> 3) ^ (m & 7);
                    Ps[m * 64 + ch * 8 + (kl & 7)] = (__bf16)sa[mi][nt][rr];
                }
            }
        }
#pragma unroll
        for (int ks = 0; ks < 2; ++ks) {
            bf16x8 af[2];
#pragma unroll
            for (int mi = 0; mi < 2; ++mi) {
                int r = w * 32 + mi * 16 + l16;
                int c = (ks * 4 + quad) ^ (r & 7);
                af[mi] = *(const bf16x8*)(Ps + r * 64 + c * 8);
            }
#pragma unroll
            for (int nt = 0; nt < 4; ++nt) {
                int dr = nt * 16 + l16;
                int vc = (8 + ks * 4 + quad) ^ (dr & 15);
                bf16x8 bv = *(const bf16x8*)(Vts + dr * 128 + vc * 8);
#pragma unroll
                for (int mi = 0; mi < 2; ++mi)
                    oa[mi][nt] = MFMA(af[mi], bv, oa[mi][nt]);
            }
        }
        __syncthreads();               // all waves done reading Ks/Vts
        if (kt < 15) { writeK(); writeV(); }
        __syncthreads();               // new tiles visible
    }

    // write attention output in (b, s, h, d) bf16 layout for the O-projection
#pragma unroll
    for (int mi = 0; mi < 2; ++mi)
#pragma unroll
        for (int nt = 0; nt < 4; ++nt)
#pragma unroll
            for (int rr = 0; rr < 4; ++rr) {
                int sg = b * S_ + q0 + w * 32 + mi * 16 + quad * 4 + rr;
                int f = h * HD_ + nt * 16 + l16;
                AO[(size_t)sg * H_ + f] = (__bf16)oa[mi][nt][rr];
            }
}

// ---------------- LayerNorm (in-place on d_out y region) ----------------
__global__ __launch_bounds__(256) void k_ln(
    float* __restrict__ x, const float* __restrict__ lw, const float* __restrict__ lb)
{
    __shared__ float red[8];
    const int row = blockIdx.x, tid = threadIdx.x;
    float4 v = *(float4*)(x + (size_t)row * H_ + tid * 4);
    float s = v.x + v.y + v.z + v.w;
    float ss = v.x * v.x + v.y * v.y + v.z * v.z + v.w * v.w;
#pragma unroll
    for (int o = 1; o < 64; o <<= 1) { s += __shfl_xor(s, o); ss += __shfl_xor(ss, o); }
    const int w = tid >> 6;
    if ((tid & 63) == 0) { red[w] = s; red[4 + w] = ss; }
    __syncthreads();
    s = red[0] + red[1] + red[2] + red[3];
    ss = red[4] + red[5] + red[6] + red[7];
    float mu = s * (1.0f / H_);
    float var = ss * (1.0f / H_) - mu * mu;
    float rstd = rsqrtf(var + 1e-6f);
    float4 wv = *(const float4*)(lw + tid * 4);
    float4 bv = *(const float4*)(lb + tid * 4);
    float4 y;
    y.x = (v.x - mu) * rstd * wv.x + bv.x;
    y.y = (v.y - mu) * rstd * wv.y + bv.y;
    y.z = (v.z - mu) * rstd * wv.z + bv.z;
    y.w = (v.w - mu) * rstd * wv.w + bv.w;
    *(float4*)(x + (size_t)row * H_ + tid * 4) = y;
}

// ---------------- launch ----------------
extern "C" void kernel_launch(void* const* d_in, const int* in_sizes, int n_in,
                              void* d_out, int out_size, void* d_ws, size_t ws_size,
                              hipStream_t stream)
{
    const float* enc  = (const float*)d_in[0];
    const float* mask = (const float*)d_in[1];
    const float* WQ   = (const float*)d_in[2];
    const float* WK   = (const float*)d_in[3];
    const float* WV   = (const float*)d_in[4];
    const float* WO   = (const float*)d_in[5];
    const float* lnw  = (const float*)d_in[6];
    const float* lnb  = (const float*)d_in[7];

    float* y    = (float*)d_out;          // [B,S,H] fp32
    float* attn = y + YSIZE;              // [B,NH,S,S] fp32

    char* ws = (char*)d_ws;
    __bf16* encb = (__bf16*)(ws);                    // 8 MB (dead after V GEMM)
    __bf16* wqb  = (__bf16*)(ws + (8ull  << 20));    // 2 MB
    __bf16* wkb  = (__bf16*)(ws + (10ull << 20));
    __bf16* wvb  = (__bf16*)(ws + (12ull << 20));
    __bf16* wob  = (__bf16*)(ws + (14ull << 20));
    __bf16* Qb   = (__bf16*)(ws + (16ull << 20));    // 8 MB  (b,h,s,d)
    __bf16* Kb   = (__bf16*)(ws + (24ull << 20));    // 8 MB  (b,h,s,d)
    __bf16* Vtb  = (__bf16*)(ws + (32ull << 20));    // 8 MB  (h,d,b,s)
    __bf16* AO   = (__bf16*)(ws + (40ull << 20));    // 8 MB  (b,s,h,d)
    // 1 MB mask bitmask overlays encb region (only live during/after k_maskbits,
    // which runs after the last consumer of encb)
    unsigned long long* mbits = (unsigned long long*)ws;

    k_convert<<<8192, 256, 0, stream>>>(enc, WQ, WK, WV, WO, encb, wqb, wkb, wvb, wob);

    dim3 gQK(8, 32);   // N=1024 tiles, M=4096 tiles
    k_gemm_nt<0><<<gQK, 256, 0, stream>>>(encb, wqb, Qb, nullptr, H_, 0,
                                          2048u, 2097152u, 64u, 64u, 131072u, 1u);
    k_gemm_nt<0><<<gQK, 256, 0, stream>>>(encb, wkb, Kb, nullptr, H_, 0,
                                          2048u, 2097152u, 64u, 64u, 131072u, 1u);
    dim3 gV(32, 8);    // N=4096 tiles, M=1024 tiles  (V^T: addr = m*4096 + n)
    k_gemm_nt<0><<<gV, 256, 0, stream>>>(wvb, encb, Vtb, nullptr, H_, 0,
                                         4096u, 0u, 4096u, 4096u, 0u, 1u);

    k_maskbits<<<B_ * S_, 256, 0, stream>>>(mask, mbits);

    k_attn<<<512, 256, 0, stream>>>(Qb, Kb, Vtb, mbits, attn, AO);

    // O-proj + residual, fp32 into d_out y region: addr = gm*1024 + gn
    k_gemm_nt<1><<<gQK, 256, 0, stream>>>(AO, wob, y, enc, H_, H_,
                                          4096u, 0u, 1024u, 1024u, 0u, 1u);

    k_ln<<<YSIZE / H_, 256, 0, stream>>>(y, lnw, lnb);
}